// Round 2
// baseline (29469.205 us; speedup 1.0000x reference)
//
#include <hip/hip_runtime.h>
#include <hip/hip_bf16.h>

// LSTM: T=512, B=128, I=512, H=1024. Persistent cooperative kernel:
// 256 WGs (1/CU) x 256 threads (4 waves). WG owns 8 hidden units x 64 batch
// rows (all 4 gates) -> c-state lives in VGPRs. W slice bf16 in LDS (once).
// Per step: bf16 MFMA gates -> pointwise -> write h (fp32 out + bf16 ping-pong)
// -> two-level grid barrier.

#define TT 512
#define BBATCH 128
#define IIN 512
#define HHID 1024
#define KK 1536            // H + I
#define WSTR 1544          // padded LDS row stride (bf16 elems), 16B-aligned rows
#define HB (BBATCH * HHID) // h buffer elems per slot

using bf16x8 = __attribute__((ext_vector_type(8))) short;
using f32x4  = __attribute__((ext_vector_type(4))) float;

static __device__ __forceinline__ short f2bf(float f) {
  unsigned x = __float_as_uint(f);
  unsigned r = (x + 0x7fffu + ((x >> 16) & 1u)) >> 16; // RNE
  return (short)r;
}
static __device__ __forceinline__ float sigm(float v) { return 1.f / (1.f + __expf(-v)); }
static __device__ __forceinline__ float tanh_(float v) { return 1.f - 2.f / (1.f + __expf(2.f * v)); }

__global__ __launch_bounds__(256, 1)
void lstm_persist(const float* __restrict__ x,
                  const float* __restrict__ Wf, const float* __restrict__ bfv,
                  const float* __restrict__ Wi, const float* __restrict__ biv,
                  const float* __restrict__ Wc, const float* __restrict__ bcv,
                  const float* __restrict__ Wo, const float* __restrict__ bov,
                  float* __restrict__ out, short* __restrict__ hbuf,
                  unsigned* __restrict__ bar)
{
  extern __shared__ char smem[];
  short* wlds = (short*)smem;                          // 32 x WSTR bf16   = 98816 B
  float* blds = (float*)(smem + 32 * WSTR * 2);        // 32 f32           = 128 B
  float* sc   = (float*)(smem + 32 * WSTR * 2 + 128);  // 4 x 16 x 33 f32  = 8448 B

  const int tid  = threadIdx.x;
  const int wg   = blockIdx.x;
  const int lane = tid & 63;
  const int wave = tid >> 6;
  const int l15  = lane & 15;
  const int lg   = lane >> 4;

  const int bh = wg & 1;            // batch half
  const int ug = wg >> 1;           // unit group 0..127
  const int u0 = ug << 3;           // first hidden unit (8 per WG)
  const int b0 = bh << 6;           // first batch row (64 per WG)
  const int bb = b0 + (wave << 4);  // this wave's 16 batch rows

  // ---- prologue: weights (fp32 -> bf16) + biases into LDS, once ----
  {
    const float* Ws[4] = {Wf, Wi, Wc, Wo};
    for (int idx = tid; idx < 32 * KK; idx += 256) {
      int r = idx / KK;
      int k = idx - r * KK;
      const float* src = Ws[r >> 3];
      wlds[r * WSTR + k] = f2bf(src[(size_t)(u0 + (r & 7)) * KK + k]);
    }
    if (tid < 32) {
      const float* bs = (tid < 8) ? bfv : (tid < 16) ? biv : (tid < 24) ? bcv : bov;
      blds[tid] = bs[u0 + (tid & 7)];
    }
  }
  __syncthreads();

  float creg0 = 0.f, creg1 = 0.f;   // cell state, 2 cells per thread

  unsigned* gen  = bar;             // generation counter
  unsigned* cnt0 = bar + 32;        // root counter (128B away)
  unsigned* cnt1 = bar + 64;        // 16 leaf counters, stride 32 u32
  const int grp = wg >> 4;

  for (int t = 0; t < TT; ++t) {
    const short* hc = hbuf + ((t & 1) ? HB : 0);
    short*       hn = hbuf + ((t & 1) ? 0 : HB);
    f32x4 acc0 = {0.f, 0.f, 0.f, 0.f};
    f32x4 acc1 = {0.f, 0.f, 0.f, 0.f};

    const short* wp = wlds + l15 * WSTR + (lg << 3);

    if (t > 0) {   // h part (K = 0..1023); t==0 has h == 0
      const short* ap = hc + ((bb + l15) << 10) + (lg << 3);
      #pragma unroll 8
      for (int ks = 0; ks < 32; ++ks) {
        bf16x8 a  = *(const bf16x8*)(ap + (ks << 5));
        bf16x8 w0 = *(const bf16x8*)(wp + (ks << 5));
        bf16x8 w1 = *(const bf16x8*)(wp + 16 * WSTR + (ks << 5));
        acc0 = __builtin_amdgcn_mfma_f32_16x16x32_bf16(a, w0, acc0, 0, 0, 0);
        acc1 = __builtin_amdgcn_mfma_f32_16x16x32_bf16(a, w1, acc1, 0, 0, 0);
      }
    }
    {   // x part (K = 1024..1535), fp32 -> bf16 inline
      const float* xp = x + ((size_t)t * BBATCH + bb + l15) * IIN + (lg << 3);
      const short* wq = wp + 1024;
      #pragma unroll 4
      for (int ks = 0; ks < 16; ++ks) {
        float4 lo = *(const float4*)(xp + (ks << 5));
        float4 hi = *(const float4*)(xp + (ks << 5) + 4);
        bf16x8 a;
        a[0] = f2bf(lo.x); a[1] = f2bf(lo.y); a[2] = f2bf(lo.z); a[3] = f2bf(lo.w);
        a[4] = f2bf(hi.x); a[5] = f2bf(hi.y); a[6] = f2bf(hi.z); a[7] = f2bf(hi.w);
        bf16x8 w0 = *(const bf16x8*)(wq + (ks << 5));
        bf16x8 w1 = *(const bf16x8*)(wq + 16 * WSTR + (ks << 5));
        acc0 = __builtin_amdgcn_mfma_f32_16x16x32_bf16(a, w0, acc0, 0, 0, 0);
        acc1 = __builtin_amdgcn_mfma_f32_16x16x32_bf16(a, w1, acc1, 0, 0, 0);
      }
    }

    // ---- epilogue: D frag (row=(lane>>4)*4+j, col=lane&15) -> LDS scratch ----
    float* scw = sc + wave * (16 * 33);
    #pragma unroll
    for (int j = 0; j < 4; ++j) {
      scw[((lg << 2) + j) * 33 + l15]      = acc0[j];
      scw[((lg << 2) + j) * 33 + 16 + l15] = acc1[j];
    }
    __syncthreads();

    #pragma unroll
    for (int cc = 0; cc < 2; ++cc) {
      int idx = lane + (cc << 6);
      int rr = idx >> 3, uu = idx & 7;
      float pf = scw[rr * 33 + uu]      + blds[uu];
      float pi = scw[rr * 33 + 8 + uu]  + blds[8 + uu];
      float pc = scw[rr * 33 + 16 + uu] + blds[16 + uu];
      float po = scw[rr * 33 + 24 + uu] + blds[24 + uu];
      float fg = sigm(pf), ig = sigm(pi), cg = tanh_(pc), og = sigm(po);
      float cold = cc ? creg1 : creg0;
      float cn = fg * cold + ig * cg;
      if (cc) creg1 = cn; else creg0 = cn;
      float h = og * tanh_(cn);
      int b = bb + rr, u = u0 + uu;
      out[((size_t)t << 17) + ((size_t)b << 10) + u] = h;
      hn[(b << 10) + u] = f2bf(h);
    }

    // ---- two-level grid barrier (device-scope) ----
    __threadfence();          // release: h stores visible device-wide
    __syncthreads();
    if (tid == 0) {
      unsigned g = __hip_atomic_load(gen, __ATOMIC_RELAXED, __HIP_MEMORY_SCOPE_AGENT);
      unsigned a = __hip_atomic_fetch_add(&cnt1[grp * 32], 1u, __ATOMIC_ACQ_REL, __HIP_MEMORY_SCOPE_AGENT);
      if (a == 15u) {
        __hip_atomic_store(&cnt1[grp * 32], 0u, __ATOMIC_RELAXED, __HIP_MEMORY_SCOPE_AGENT);
        unsigned r = __hip_atomic_fetch_add(cnt0, 1u, __ATOMIC_ACQ_REL, __HIP_MEMORY_SCOPE_AGENT);
        if (r == 15u) {
          __hip_atomic_store(cnt0, 0u, __ATOMIC_RELAXED, __HIP_MEMORY_SCOPE_AGENT);
          __hip_atomic_fetch_add(gen, 1u, __ATOMIC_ACQ_REL, __HIP_MEMORY_SCOPE_AGENT);
        } else {
          while (__hip_atomic_load(gen, __ATOMIC_RELAXED, __HIP_MEMORY_SCOPE_AGENT) == g)
            __builtin_amdgcn_s_sleep(2);
        }
      } else {
        while (__hip_atomic_load(gen, __ATOMIC_RELAXED, __HIP_MEMORY_SCOPE_AGENT) == g)
          __builtin_amdgcn_s_sleep(2);
      }
    }
    __syncthreads();
    __threadfence();          // acquire: invalidate stale h lines
  }
}

extern "C" void kernel_launch(void* const* d_in, const int* in_sizes, int n_in,
                              void* d_out, int out_size, void* d_ws, size_t ws_size,
                              hipStream_t stream) {
  const float* x   = (const float*)d_in[0];
  const float* Wf  = (const float*)d_in[1];
  const float* bfv = (const float*)d_in[2];
  const float* Wi  = (const float*)d_in[3];
  const float* biv = (const float*)d_in[4];
  const float* Wc  = (const float*)d_in[5];
  const float* bcv = (const float*)d_in[6];
  const float* Wo  = (const float*)d_in[7];
  const float* bov = (const float*)d_in[8];
  float* out = (float*)d_out;

  // ws: [0..4096) barrier counters (zeroed), [4096..) h ping-pong (2*128*1024 bf16)
  unsigned* bar = (unsigned*)d_ws;
  short* hbuf = (short*)((char*)d_ws + 4096);
  hipMemsetAsync(d_ws, 0, 4096, stream);

  const int shmem = 32 * WSTR * 2 + 128 + 4 * 16 * 33 * 4; // 107392 B
  hipFuncSetAttribute((const void*)lstm_persist,
                      hipFuncAttributeMaxDynamicSharedMemorySize, shmem);

  void* args[] = {(void*)&x, (void*)&Wf, (void*)&bfv, (void*)&Wi, (void*)&biv,
                  (void*)&Wc, (void*)&bcv, (void*)&Wo, (void*)&bov,
                  (void*)&out, (void*)&hbuf, (void*)&bar};
  hipLaunchCooperativeKernel((const void*)lstm_persist, dim3(256), dim3(256),
                             args, shmem, stream);
}